// Round 18
// baseline (408.209 us; speedup 1.0000x reference)
//
#include <hip/hip_runtime.h>
#include <hip/hip_bf16.h>
#include <stdint.h>

typedef unsigned short u16;
typedef __attribute__((ext_vector_type(8))) __bf16 bf16x8;
typedef __attribute__((ext_vector_type(4))) float f32x4;

#define EPSF 1e-6f
#define SCALE 0.08838834764831845f   // 128^-0.5

__device__ __forceinline__ u16 f2bf(float f) {
    union { float f; uint32_t u; } a; a.f = f;
    uint32_t r = a.u + 0x7FFFu + ((a.u >> 16) & 1u);   // RNE
    return (u16)(r >> 16);
}
__device__ __forceinline__ float bf2f(u16 u) {
    union { uint32_t u; float f; } a; a.u = ((uint32_t)u) << 16;
    return a.f;
}
__device__ __forceinline__ u16 f2bf_n(float f) {     // native cvt (RNE), packable
    __hip_bfloat16 h = __float2bfloat16(f);
    return *reinterpret_cast<u16*>(&h);
}

// ---------------- fused f32 -> bf16 cast of hidden + qkv_w + o_w ----------------
__global__ __launch_bounds__(256) void cvt_all_k(
    const float* __restrict__ a,   // hidden:   4194304 float4
    const float* __restrict__ b,   // qkv_w:    2097152 float4
    const float* __restrict__ c,   // o_w:      1048576 float4
    u16* __restrict__ out)
{
    long i = (long)blockIdx.x * 256 + threadIdx.x;   // float4 index, < 7340032
    const float* src; long off;
    if (i < 4194304L)      { src = a; off = 0; }
    else if (i < 6291456L) { src = b; off = 4194304L; }
    else                   { src = c; off = 6291456L; }
    float4 v = ((const float4*)src)[i - off];
    ushort4 o;
    o.x = f2bf(v.x); o.y = f2bf(v.y); o.z = f2bf(v.z); o.w = f2bf(v.w);
    ((ushort4*)out)[i] = o;
}

__device__ __forceinline__ void gload16(const u16* g, u16* l) {
    __builtin_amdgcn_global_load_lds(
        (const __attribute__((address_space(1))) uint32_t*)g,
        (__attribute__((address_space(3))) uint32_t*)l, 16, 0, 0);
}

// ---------------- 128x128 NT GEMM: C[M][N] = A[M][K] * B[N][K]^T (+bias) ----
// 2-barrier loop with the catalog-optimal 128^2 tile (table: 128^2=912 TF vs
// 256^2=792 at this structure). 256 thr = 4 waves (2Mx2N), BK=64, LDS 64KB
// double-buffered -> 2 blocks/CU (co-resident blocks hide each other's
// barrier drains, m114 mechanism). R10 ledger kept: full next-tile STAGE at
// iteration top -> vmcnt(8) drains exactly tile kt's 8 loads (a full
// iteration of flight). T2 XOR swizzle on the global SOURCE (LDS linear).
__global__ __launch_bounds__(256, 2) void gemm4_nt(
    const u16* __restrict__ A, const u16* __restrict__ B,
    const float* __restrict__ bias,
    float* __restrict__ Cf, u16* __restrict__ Cb,
    int M, int N, int K)
{
    __shared__ u16 As[2][128 * 64];
    __shared__ u16 Bs[2][128 * 64];

    const int t = threadIdx.x;
    const int lane = t & 63;
    const int g = lane >> 4, lr = lane & 15;
    const int w = t >> 6;                // 0..3
    const int wm = w >> 1, wn = w & 1;   // 2 x 2 wave grid

    // T1: XCD-aware block swizzle (nwg % 8 == 0 for both call sites)
    const int nwg = gridDim.x * gridDim.y;
    const int bid0 = blockIdx.y * gridDim.x + blockIdx.x;
    const int cpx = nwg >> 3;
    const int bids = (bid0 & 7) * cpx + (bid0 >> 3);
    const int bn = (bids % gridDim.x) * 128;
    const int bm = (bids / gridDim.x) * 128;
    const int NT = K >> 6;

    f32x4 z = {0.f, 0.f, 0.f, 0.f};
    f32x4 acc[4][4];
#pragma unroll
    for (int m = 0; m < 4; ++m)
#pragma unroll
        for (int n = 0; n < 4; ++n) acc[m][n] = z;

    // full K-tile stage: A tile 128x64 (1024 chunks) + B tile (1024 chunks),
    // 8 gloads/thread; source pre-swizzled (involution csrc = slot ^ (row&7)).
    auto STAGEALL = [&](int buf, int k0) {
#pragma unroll
        for (int j = 0; j < 8; ++j) {
            int idx = j * 256 + t;           // 0..2047
            int ci = idx & 1023;
            int row = ci >> 3, slot = ci & 7;
            int csrc = slot ^ (row & 7);
            if (idx < 1024)
                gload16(A + (size_t)(bm + row) * K + k0 + csrc * 8, &As[buf][0] + ci * 8);
            else
                gload16(B + (size_t)(bn + row) * K + k0 + csrc * 8, &Bs[buf][0] + ci * 8);
        }
    };

    STAGEALL(0, 0);   // prologue

    for (int kt = 0; kt < NT; ++kt) {
        const int cur = kt & 1;
        const int k0n = (kt + 1) << 6;
        const bool last = (kt == NT - 1);
        const char* Ab = (const char*)&As[cur][0];
        const char* Bb = (const char*)&Bs[cur][0];
        const int swz = (lr & 7) << 4;

        // ---- stage the ENTIRE next K-tile, then wait for cur's loads ----
        if (!last) {
            STAGEALL(cur ^ 1, k0n);
            asm volatile("s_waitcnt vmcnt(8)" ::: "memory");   // cur's 8 landed; next's 8 in flight
        } else {
            asm volatile("s_waitcnt vmcnt(0)" ::: "memory");
        }
        __builtin_amdgcn_s_barrier();        // RAW: all waves' cur-tile loads landed
        __builtin_amdgcn_sched_barrier(0);   // no ds_read hoists above the barrier

        // ---- fragment reads (16 x ds_read_b128) + 32 MFMA ----
        bf16x8 afr[4][2], bfr[4][2];
#pragma unroll
        for (int mi = 0; mi < 4; ++mi) {
            int row = wm * 64 + mi * 16 + lr;
#pragma unroll
            for (int kc = 0; kc < 2; ++kc)
                afr[mi][kc] = *(const bf16x8*)(Ab + row * 128 + ((kc * 64 + g * 16) ^ swz));
        }
#pragma unroll
        for (int ni = 0; ni < 4; ++ni) {
            int row = wn * 64 + ni * 16 + lr;
#pragma unroll
            for (int kc = 0; kc < 2; ++kc)
                bfr[ni][kc] = *(const bf16x8*)(Bb + row * 128 + ((kc * 64 + g * 16) ^ swz));
        }
        __builtin_amdgcn_s_setprio(1);
#pragma unroll
        for (int mi = 0; mi < 4; ++mi)
#pragma unroll
            for (int ni = 0; ni < 4; ++ni)
#pragma unroll
                for (int kc = 0; kc < 2; ++kc)
                    acc[mi][ni] = __builtin_amdgcn_mfma_f32_16x16x32_bf16(
                        afr[mi][kc], bfr[ni][kc], acc[mi][ni], 0, 0, 0);
        __builtin_amdgcn_s_setprio(0);

        __builtin_amdgcn_sched_barrier(0);   // no MFMA/read sinks below the barrier
        __builtin_amdgcn_s_barrier();        // WAR: done reading cur before next iter stages into it
    }

#pragma unroll
    for (int mf = 0; mf < 4; ++mf) {
#pragma unroll
        for (int nf = 0; nf < 4; ++nf) {
            int col = bn + wn * 64 + nf * 16 + lr;
            float bv = bias ? bias[col] : 0.f;
#pragma unroll
            for (int r = 0; r < 4; ++r) {
                int row = bm + wm * 64 + mf * 16 + g * 4 + r;   // C/D: row=(l>>4)*4+reg, col=l&15
                float v = acc[mf][nf][r] + bv;
                if (Cf) Cf[(size_t)row * N + col] = v;
                else    Cb[(size_t)row * N + col] = f2bf(v);
            }
        }
    }
}

// ---------------- fused prep: RMS norm (q/k heads) + V transpose ----------------
__global__ __launch_bounds__(256) void prep_k(
    u16* __restrict__ qkv, const float* __restrict__ qw, const float* __restrict__ kw,
    u16* __restrict__ vt)
{
    __shared__ u16 T[64 * 64];
    const int bid = blockIdx.x;
    const int t = threadIdx.x;

    if (bid < 8192) {
        const int row = bid;
        const int w = t >> 6, l = t & 63;
#pragma unroll
        for (int i = 0; i < 6; ++i) {
            int head = w + i * 4;               // 0..23 (16 q + 8 k)
            const float* wt = (head < 16) ? qw : kw;
            u16* p = qkv + (size_t)row * 4096 + head * 128;
            uint32_t u = *(const uint32_t*)(p + l * 2);
            float x0 = bf2f((u16)(u & 0xFFFF));
            float x1 = bf2f((u16)(u >> 16));
            float ss = x0 * x0 + x1 * x1;
#pragma unroll
            for (int m = 1; m < 64; m <<= 1) ss += __shfl_xor(ss, m, 64);
            float inv = rsqrtf(ss * (1.0f / 128.0f) + EPSF);
            float r0 = x0 * inv * wt[l * 2];
            float r1 = x1 * inv * wt[l * 2 + 1];
            uint32_t o = (uint32_t)f2bf(r0) | ((uint32_t)f2bf(r1) << 16);
            *(uint32_t*)(p + l * 2) = o;
        }
    } else {
        const int q = bid - 8192;               // 0..2047 = 32(sx) x 2(dy) x 32(z)
        const int sx = (q & 31) * 64;
        const int dy = ((q >> 5) & 1) * 64;
        const int z  = q >> 6;                  // b*8+hk
        const int b = z >> 3, hk = z & 7;
#pragma unroll
        for (int j = 0; j < 2; ++j) {
            int idx = t + j * 256;
            int r = idx >> 3, c8 = (idx & 7) * 8;
            uint4 v = *(const uint4*)(qkv + (size_t)(b * 2048 + sx + r) * 4096 + 3072 + hk * 128 + dy + c8);
            int slot = (c8 >> 3) ^ ((r ^ (r >> 3)) & 7);
            *(uint4*)(&T[r * 64 + slot * 8]) = v;
        }
        __syncthreads();
#pragma unroll
        for (int j = 0; j < 2; ++j) {
            int idx = t + j * 256;
            int rr = idx >> 3, cc8 = (idx & 7) * 8;
            u16 tmp[8];
#pragma unroll
            for (int i = 0; i < 8; ++i) {
                int row = cc8 + i;
                int slot = (rr >> 3) ^ ((row ^ (row >> 3)) & 7);
                tmp[i] = T[row * 64 + slot * 8 + (rr & 7)];
            }
            *(uint4*)(vt + ((size_t)z * 128 + dy + rr) * 2048 + sx + cc8) = *(uint4*)tmp;
        }
    }
}

// ---------------- flash attention v7 (causal, GQA 2:1) ----------------
// R13 schedule (double-buffered K/V, ONE barrier per visit), swapped-QK
// in-register softmax (R17-verified): lane (g,lr) owns q-row lr; row-max =
// 15 in-lane fmax + 2 shfl; P packed to bf16 in-register; PV A-fragments
// assembled by a 2-round shfl exchange (no P LDS buffer).
__global__ __launch_bounds__(256, 2) void attn7_k(
    const u16* __restrict__ qkv, const u16* __restrict__ vt,
    u16* __restrict__ aout)
{
    __shared__ u16 Kt[2][64 * 128];
    __shared__ u16 Vl[2][128 * 64];

    const int t = threadIdx.x;
    const int lane = t & 63;
    const int w = t >> 6;
    const int g = lane >> 4, lr = lane & 15;
    const int pr = blockIdx.x, h = blockIdx.y, b = blockIdx.z;
    const int hk = h >> 1;
    const size_t rowb = (size_t)b * 2048;

    const u16* ksrc = qkv + rowb * 4096 + 2048 + hk * 128;
    const u16* vsrc = vt + (size_t)(b * 8 + hk) * 128 * 2048;

    bf16x8 ones8;
    {
        union { bf16x8 v; u16 e[8]; } on;
#pragma unroll
        for (int j = 0; j < 8; ++j) on.e[j] = 0x3F80;   // bf16 1.0
        ones8 = on.v;
    }

    auto STAGE = [&](int buf, int kvb) {
#pragma unroll
        for (int j = 0; j < 4; ++j) {
            int idx = t + j * 256;
            {   // K: row = idx>>4 (0..63), slot = idx&15; swizzle low 3 chunk bits
                int row = idx >> 4, slot = idx & 15;
                int csrc = (slot & 8) | ((slot & 7) ^ (row & 7));
                gload16(ksrc + (size_t)(kvb + row) * 4096 + csrc * 8, &Kt[buf][0] + idx * 8);
            }
            {   // V: row = idx>>3 (0..127 d-rows), slot = idx&7
                int row = idx >> 3, slot = idx & 7;
                int csrc = slot ^ (row & 7);
                gload16(vsrc + (size_t)row * 2048 + kvb + csrc * 8, &Vl[buf][0] + idx * 8);
            }
        }
    };

    for (int sub = 0; sub < 2; ++sub) {
        const int qt = sub ? 15 - pr : pr;
        const int qbase = qt * 128;
        const int nt = 2 * qt + 2;

        // Q fragments for both 16-row sub-blocks, pre-scaled by SCALE
        bf16x8 qf[2][4];
        {
            const u16* qp = qkv + (rowb + qbase + w * 32 + lr) * 4096 + h * 128;
#pragma unroll
            for (int sb = 0; sb < 2; ++sb)
#pragma unroll
                for (int c = 0; c < 4; ++c) {
                    union { bf16x8 v; u16 e[8]; } uq;
                    uq.v = *(const bf16x8*)(qp + sb * 16 * 4096 + c * 32 + g * 8);
#pragma unroll
                    for (int jj = 0; jj < 8; ++jj) uq.e[jj] = f2bf(bf2f(uq.e[jj]) * SCALE);
                    qf[sb][c] = uq.v;
                }
        }

        float m_r2[2];                       // running max of THIS lane's q-row
        f32x4 z = {0.f, 0.f, 0.f, 0.f};
        f32x4 l_acc[2];
        f32x4 o_acc[2][8];
#pragma unroll
        for (int sb = 0; sb < 2; ++sb) {
            m_r2[sb] = -INFINITY;
            l_acc[sb] = z;
#pragma unroll
            for (int d = 0; d < 8; ++d) o_acc[sb][d] = z;
        }

        __syncthreads();   // WAR vs previous sub's last-visit reads
        STAGE(0, 0);       // prologue into buf0

        for (int kt = 0; kt < nt; ++kt) {
            const int cur = kt & 1;
            const int kvb = kt * 64;
            asm volatile("s_waitcnt vmcnt(0)" ::: "memory");   // visit-kt loads landed
            __builtin_amdgcn_s_barrier();       // RAW for all waves + WAR for buf[cur^1]
            __builtin_amdgcn_sched_barrier(0);
            if (kt + 1 < nt) STAGE(cur ^ 1, kvb + 64);   // next tile: full-visit flight
            __builtin_amdgcn_sched_barrier(0);

            const u16* Kc = &Kt[cur][0];
            const u16* Vc = &Vl[cur][0];
            const bool active = !(kt == nt - 1 && w < 2);
            const bool near = (kt >= nt - 2);

            if (active) {
                // S^T = K Q^T for both sub-blocks (same fragment reads, swapped roles)
                f32x4 st[2][4];
                __builtin_amdgcn_s_setprio(1);
#pragma unroll
                for (int cb = 0; cb < 4; ++cb) {
                    int row = cb * 16 + lr;
                    st[0][cb] = z; st[1][cb] = z;
#pragma unroll
                    for (int c = 0; c < 4; ++c) {
                        int chunk = c * 4 + g;
                        int slot = (chunk & 8) | ((chunk & 7) ^ (row & 7));
                        bf16x8 kf = *(const bf16x8*)(&Kc[row * 128 + slot * 8]);
                        st[0][cb] = __builtin_amdgcn_mfma_f32_16x16x32_bf16(kf, qf[0][c], st[0][cb], 0, 0, 0);
                        st[1][cb] = __builtin_amdgcn_mfma_f32_16x16x32_bf16(kf, qf[1][c], st[1][cb], 0, 0, 0);
                    }
                }
                __builtin_amdgcn_s_setprio(0);

                const int slo = ((g & 1) << 5) + lr;   // source lane pair for PV assembly
                const int shi = slo + 16;
                const bool ghx = (g >> 1) & 1;         // g in {2,3} -> consume cb = 2kk+1

#pragma unroll
                for (int sb = 0; sb < 2; ++sb) {
                    const int qa = qbase + w * 32 + sb * 16 + lr;   // this lane's q-row
                    if (near) {
#pragma unroll
                        for (int cb = 0; cb < 4; ++cb)
#pragma unroll
                            for (int r = 0; r < 4; ++r)
                                if (kvb + cb * 16 + g * 4 + r > qa) st[sb][cb][r] = -INFINITY;
                    }
                    // row max: 15 in-lane + combine the 4 g-copies
                    f32x4 m4;
#pragma unroll
                    for (int e = 0; e < 4; ++e)
                        m4[e] = fmaxf(fmaxf(st[sb][0][e], st[sb][1][e]),
                                      fmaxf(st[sb][2][e], st[sb][3][e]));
                    float mx = fmaxf(fmaxf(m4[0], m4[1]), fmaxf(m4[2], m4[3]));
                    mx = fmaxf(mx, __shfl_xor(mx, 16));
                    mx = fmaxf(mx, __shfl_xor(mx, 32));
                    float mold = m_r2[sb];
                    float mbase;
                    if (__all(mx <= mold + 8.0f)) {
                        mbase = mold;               // T13 defer-max: skip rescale
                    } else {
                        float mnew = fmaxf(mold, mx);
                        float alpha = __expf(mold - mnew);
#pragma unroll
                        for (int r = 0; r < 4; ++r) {
                            float ar = __shfl(alpha, (lane & 48) | (g * 4 + r), 64);
                            l_acc[sb][r] *= ar;
#pragma unroll
                            for (int d = 0; d < 8; ++d) o_acc[sb][d][r] *= ar;
                        }
                        m_r2[sb] = mnew;
                        mbase = mnew;
                    }
                    // P pack: pk[cb] = bf16(p_r0..p_r3) of this lane's kv slots
                    uint2 pk[4];
#pragma unroll
                    for (int cb = 0; cb < 4; ++cb) {
                        float p0 = __expf(st[sb][cb][0] - mbase);
                        float p1 = __expf(st[sb][cb][1] - mbase);
                        float p2 = __expf(st[sb][cb][2] - mbase);
                        float p3 = __expf(st[sb][cb][3] - mbase);
                        pk[cb].x = (uint32_t)f2bf_n(p0) | ((uint32_t)f2bf_n(p1) << 16);
                        pk[cb].y = (uint32_t)f2bf_n(p2) | ((uint32_t)f2bf_n(p3) << 16);
                    }

                    // O += P V; l += P x ones (pa assembled in-register)
#pragma unroll
                    for (int kk = 0; kk < 2; ++kk) {
                        uint32_t e0 = (uint32_t)__shfl((int)pk[kk * 2].x, slo, 64);
                        uint32_t e1 = (uint32_t)__shfl((int)pk[kk * 2].y, slo, 64);
                        uint32_t e2 = (uint32_t)__shfl((int)pk[kk * 2].x, shi, 64);
                        uint32_t e3 = (uint32_t)__shfl((int)pk[kk * 2].y, shi, 64);
                        uint32_t o0 = (uint32_t)__shfl((int)pk[kk * 2 + 1].x, slo, 64);
                        uint32_t o1 = (uint32_t)__shfl((int)pk[kk * 2 + 1].y, slo, 64);
                        uint32_t o2 = (uint32_t)__shfl((int)pk[kk * 2 + 1].x, shi, 64);
                        uint32_t o3 = (uint32_t)__shfl((int)pk[kk * 2 + 1].y, shi, 64);
                        union { uint32_t u[4]; bf16x8 v; } pa;
                        pa.u[0] = ghx ? o0 : e0;
                        pa.u[1] = ghx ? o1 : e1;
                        pa.u[2] = ghx ? o2 : e2;
                        pa.u[3] = ghx ? o3 : e3;
                        __builtin_amdgcn_s_setprio(1);
                        l_acc[sb] = __builtin_amdgcn_mfma_f32_16x16x32_bf16(pa.v, ones8, l_acc[sb], 0, 0, 0);
#pragma unroll
                        for (int d = 0; d < 8; ++d) {
                            int row = d * 16 + lr;
                            int slot = (kk * 4 + g) ^ (row & 7);
                            bf16x8 vf = *(const bf16x8*)(&Vc[row * 64 + slot * 8]);
                            o_acc[sb][d] = __builtin_amdgcn_mfma_f32_16x16x32_bf16(pa.v, vf, o_acc[sb][d], 0, 0, 0);
                        }
                        __builtin_amdgcn_s_setprio(0);
                    }
                }
            }
            __builtin_amdgcn_sched_barrier(0);
            // no trailing barrier: next visit's entry barrier provides the sync
        }

#pragma unroll
        for (int sb = 0; sb < 2; ++sb) {
            const int qrow0 = qbase + w * 32 + sb * 16 + g * 4;
#pragma unroll
            for (int r = 0; r < 4; ++r) {
                float inv = 1.0f / l_acc[sb][r];
                u16* op = aout + (rowb + qrow0 + r) * 2048 + h * 128;
#pragma unroll
                for (int d = 0; d < 8; ++d)
                    op[d * 16 + lr] = f2bf_n(o_acc[sb][d][r] * inv);
            }
        }
    }
}

// ---------------- launcher ----------------
extern "C" void kernel_launch(void* const* d_in, const int* in_sizes, int n_in,
                              void* d_out, int out_size, void* d_ws, size_t ws_size,
                              hipStream_t stream)
{
    const float* hidden = (const float*)d_in[0];
    const float* qkv_w = (const float*)d_in[7];
    const float* qkv_b = (const float*)d_in[8];
    const float* o_w   = (const float*)d_in[9];
    const float* q_nw  = (const float*)d_in[10];
    const float* k_nw  = (const float*)d_in[11];

    char* ws = (char*)d_ws;
    u16* hid_bf  = (u16*)ws; ws += (size_t)8192 * 2048 * 2;
    u16* wqkv_bf = (u16*)ws; ws += (size_t)4096 * 2048 * 2;
    u16* ow_bf   = (u16*)ws; ws += (size_t)2048 * 2048 * 2;
    u16* qkv_bf  = (u16*)ws; ws += (size_t)8192 * 4096 * 2;
    u16* attn_bf = (u16*)ws; ws += (size_t)8192 * 2048 * 2;
    // vt aliases hid_bf: hidden-bf16 is dead after the QKV GEMM, and every
    // call rewrites hid_bf before use -> deterministic across graph replays.
    u16* vt_bf   = hid_bf;   // needs 16.78 MB < hid_bf's 33.55 MB

    // fused cast of all three f32 operands (dests contiguous at hid_bf)
    cvt_all_k<<<28672, 256, 0, stream>>>(hidden, qkv_w, o_w, hid_bf);

    // qkv = hidden @ qkv_w^T + b   -> bf16 [8192][4096]
    gemm4_nt<<<dim3(32, 64), 256, 0, stream>>>(hid_bf, wqkv_bf, qkv_b,
                                               nullptr, qkv_bf, 8192, 4096, 2048);
    // fused: RMS norm q/k heads (blocks 0..8191) + V transpose (blocks 8192..10239)
    prep_k<<<dim3(10240), 256, 0, stream>>>(qkv_bf, q_nw, k_nw, vt_bf);
    // flash attention -> bf16 [8192][2048]
    attn7_k<<<dim3(8, 16, 4), 256, 0, stream>>>(qkv_bf, vt_bf, attn_bf);
    // out = attn @ o_w^T -> fp32 d_out
    gemm4_nt<<<dim3(16, 64), 256, 0, stream>>>(attn_bf, ow_bf, nullptr,
                                               (float*)d_out, nullptr, 8192, 2048, 2048);
}

// Round 19
// 377.734 us; speedup vs baseline: 1.0807x; 1.0807x over previous
//
#include <hip/hip_runtime.h>
#include <hip/hip_bf16.h>
#include <stdint.h>

typedef unsigned short u16;
typedef __attribute__((ext_vector_type(8))) __bf16 bf16x8;
typedef __attribute__((ext_vector_type(4))) float f32x4;

#define EPSF 1e-6f
#define SCALE 0.08838834764831845f   // 128^-0.5

__device__ __forceinline__ u16 f2bf(float f) {
    union { float f; uint32_t u; } a; a.f = f;
    uint32_t r = a.u + 0x7FFFu + ((a.u >> 16) & 1u);   // RNE
    return (u16)(r >> 16);
}
__device__ __forceinline__ float bf2f(u16 u) {
    union { uint32_t u; float f; } a; a.u = ((uint32_t)u) << 16;
    return a.f;
}
__device__ __forceinline__ u16 f2bf_n(float f) {     // native cvt (RNE), packable
    __hip_bfloat16 h = __float2bfloat16(f);
    return *reinterpret_cast<u16*>(&h);
}

// ---------------- fused f32 -> bf16 cast of hidden + qkv_w + o_w ----------------
__global__ __launch_bounds__(256) void cvt_all_k(
    const float* __restrict__ a,   // hidden:   4194304 float4
    const float* __restrict__ b,   // qkv_w:    2097152 float4
    const float* __restrict__ c,   // o_w:      1048576 float4
    u16* __restrict__ out)
{
    long i = (long)blockIdx.x * 256 + threadIdx.x;   // float4 index, < 7340032
    const float* src; long off;
    if (i < 4194304L)      { src = a; off = 0; }
    else if (i < 6291456L) { src = b; off = 4194304L; }
    else                   { src = c; off = 6291456L; }
    float4 v = ((const float4*)src)[i - off];
    ushort4 o;
    o.x = f2bf(v.x); o.y = f2bf(v.y); o.z = f2bf(v.z); o.w = f2bf(v.w);
    ((ushort4*)out)[i] = o;
}

__device__ __forceinline__ void gload16(const u16* g, u16* l) {
    __builtin_amdgcn_global_load_lds(
        (const __attribute__((address_space(1))) uint32_t*)g,
        (__attribute__((address_space(3))) uint32_t*)l, 16, 0, 0);
}

// ---------------- 256x256 NT GEMM: C[M][N] = A[M][K] * B[N][K]^T (+bias) ----
// R10/R13 structure (measured best: 179.5 us QKV @ MfmaUtil 32, 760 TF =
// this 2-phase structure's regime ceiling). 512 thr = 8 waves (2Mx4N),
// BK=64, LDS 128KB double-buffered, T2 XOR swizzle (slot ^= row&7 on the
// global SOURCE; LDS dest linear). Full next-tile STAGE at iteration top ->
// vmcnt(8) drains exactly tile kt's 8 loads (a full iteration of flight).
// 2 barriers per K-tile. R18 lesson: 128^2 tile halves reuse (FETCH x1.9)
// without raising occupancy -> 256^2 is right for this structure.
__global__ __launch_bounds__(512, 2) void gemm8_nt(
    const u16* __restrict__ A, const u16* __restrict__ B,
    const float* __restrict__ bias,
    float* __restrict__ Cf, u16* __restrict__ Cb,
    int M, int N, int K)
{
    __shared__ u16 As[2][256 * 64];
    __shared__ u16 Bs[2][256 * 64];

    const int t = threadIdx.x;
    const int lane = t & 63;
    const int g = lane >> 4, lr = lane & 15;
    const int w = t >> 6;                // 0..7
    const int wm = w >> 2, wn = w & 3;   // 2 x 4 wave grid

    const int nwg = gridDim.x * gridDim.y;
    const int bid0 = blockIdx.y * gridDim.x + blockIdx.x;
    const int cpx = nwg >> 3;
    const int bids = (bid0 & 7) * cpx + (bid0 >> 3);
    const int bn = (bids % gridDim.x) * 256;
    const int bm = (bids / gridDim.x) * 256;
    const int NT = K >> 6;

    f32x4 z = {0.f, 0.f, 0.f, 0.f};
    f32x4 acc[8][4];
#pragma unroll
    for (int m = 0; m < 8; ++m)
#pragma unroll
        for (int n = 0; n < 4; ++n) acc[m][n] = z;

    auto STAGE2 = [&](int buf, int k0, int p) {
#pragma unroll
        for (int j = 0; j < 2; ++j) {
            int idx = p * 1024 + j * 512 + t;
            int ci = idx & 2047;
            int row = ci >> 3, slot = ci & 7;
            int csrc = slot ^ (row & 7);           // pre-swizzled source (involution)
            if (idx < 2048)
                gload16(A + (size_t)(bm + row) * K + k0 + csrc * 8, &As[buf][0] + ci * 8);
            else
                gload16(B + (size_t)(bn + row) * K + k0 + csrc * 8, &Bs[buf][0] + ci * 8);
        }
    };

    bf16x8 afr0[4][2], afr1[4][2];   // M-half 0 / 1 A fragments (independent sets)
    bf16x8 bf0[2][2], bf1[2][2];     // N-half 0 / 1 B fragments (retained)

#pragma unroll
    for (int p = 0; p < 4; ++p) STAGE2(0, 0, p);

    for (int kt = 0; kt < NT; ++kt) {
        const int cur = kt & 1;
        const int k0n = (kt + 1) << 6;
        const bool last = (kt == NT - 1);
        const char* Ab = (const char*)&As[cur][0];
        const char* Bb = (const char*)&Bs[cur][0];
        const int swz = (lr & 7) << 4;

        auto LDA = [&](bf16x8 (&dst)[4][2], int mbase) {
#pragma unroll
            for (int mi = 0; mi < 4; ++mi) {
                int row = wm * 128 + (mbase + mi) * 16 + lr;
#pragma unroll
                for (int kc = 0; kc < 2; ++kc)
                    dst[mi][kc] = *(const bf16x8*)(Ab + row * 128 + ((kc * 64 + g * 16) ^ swz));
            }
        };
        auto LDB = [&](bf16x8 (&dst)[2][2], int nbase) {
#pragma unroll
            for (int ni = 0; ni < 2; ++ni) {
                int row = wn * 64 + (nbase + ni) * 16 + lr;
#pragma unroll
                for (int kc = 0; kc < 2; ++kc)
                    dst[ni][kc] = *(const bf16x8*)(Bb + row * 128 + ((kc * 64 + g * 16) ^ swz));
            }
        };
        auto MMA = [&](bf16x8 (&amf)[4][2], int mf0, int nf0, bf16x8 (&bfr)[2][2]) {
            __builtin_amdgcn_s_setprio(1);
#pragma unroll
            for (int mi = 0; mi < 4; ++mi)
#pragma unroll
                for (int ni = 0; ni < 2; ++ni)
#pragma unroll
                    for (int kc = 0; kc < 2; ++kc)
                        acc[mf0 + mi][nf0 + ni] = __builtin_amdgcn_mfma_f32_16x16x32_bf16(
                            amf[mi][kc], bfr[ni][kc], acc[mf0 + mi][nf0 + ni], 0, 0, 0);
            __builtin_amdgcn_s_setprio(0);
        };

        if (!last) {
#pragma unroll
            for (int p = 0; p < 4; ++p) STAGE2(cur ^ 1, k0n, p);
            asm volatile("s_waitcnt vmcnt(8)" ::: "memory");   // cur's 8 landed; next's 8 in flight
        } else {
            asm volatile("s_waitcnt vmcnt(0)" ::: "memory");
        }
        __builtin_amdgcn_s_barrier();        // RAW: all waves' cur-tile loads landed
        __builtin_amdgcn_sched_barrier(0);

        LDA(afr0, 0); LDB(bf0, 0); LDB(bf1, 2);
        MMA(afr0, 0, 0, bf0);
        MMA(afr0, 0, 2, bf1);
        LDA(afr1, 4);
        MMA(afr1, 4, 2, bf1);
        MMA(afr1, 4, 0, bf0);

        __builtin_amdgcn_sched_barrier(0);
        __builtin_amdgcn_s_barrier();        // WAR: done reading cur before next iter stages into it
    }

#pragma unroll
    for (int mf = 0; mf < 8; ++mf) {
#pragma unroll
        for (int nf = 0; nf < 4; ++nf) {
            int col = bn + wn * 64 + nf * 16 + lr;
            float bv = bias ? bias[col] : 0.f;
#pragma unroll
            for (int r = 0; r < 4; ++r) {
                int row = bm + wm * 128 + mf * 16 + g * 4 + r;   // C/D: row=(l>>4)*4+reg, col=l&15
                float v = acc[mf][nf][r] + bv;
                if (Cf) Cf[(size_t)row * N + col] = v;
                else    Cb[(size_t)row * N + col] = f2bf(v);
            }
        }
    }
}

// ---------------- fused prep: RMS norm (q/k heads) + V transpose ----------------
__global__ __launch_bounds__(256) void prep_k(
    u16* __restrict__ qkv, const float* __restrict__ qw, const float* __restrict__ kw,
    u16* __restrict__ vt)
{
    __shared__ u16 T[64 * 64];
    const int bid = blockIdx.x;
    const int t = threadIdx.x;

    if (bid < 8192) {
        const int row = bid;
        const int w = t >> 6, l = t & 63;
#pragma unroll
        for (int i = 0; i < 6; ++i) {
            int head = w + i * 4;               // 0..23 (16 q + 8 k)
            const float* wt = (head < 16) ? qw : kw;
            u16* p = qkv + (size_t)row * 4096 + head * 128;
            uint32_t u = *(const uint32_t*)(p + l * 2);
            float x0 = bf2f((u16)(u & 0xFFFF));
            float x1 = bf2f((u16)(u >> 16));
            float ss = x0 * x0 + x1 * x1;
#pragma unroll
            for (int m = 1; m < 64; m <<= 1) ss += __shfl_xor(ss, m, 64);
            float inv = rsqrtf(ss * (1.0f / 128.0f) + EPSF);
            float r0 = x0 * inv * wt[l * 2];
            float r1 = x1 * inv * wt[l * 2 + 1];
            uint32_t o = (uint32_t)f2bf(r0) | ((uint32_t)f2bf(r1) << 16);
            *(uint32_t*)(p + l * 2) = o;
        }
    } else {
        const int q = bid - 8192;               // 0..2047 = 32(sx) x 2(dy) x 32(z)
        const int sx = (q & 31) * 64;
        const int dy = ((q >> 5) & 1) * 64;
        const int z  = q >> 6;                  // b*8+hk
        const int b = z >> 3, hk = z & 7;
#pragma unroll
        for (int j = 0; j < 2; ++j) {
            int idx = t + j * 256;
            int r = idx >> 3, c8 = (idx & 7) * 8;
            uint4 v = *(const uint4*)(qkv + (size_t)(b * 2048 + sx + r) * 4096 + 3072 + hk * 128 + dy + c8);
            int slot = (c8 >> 3) ^ ((r ^ (r >> 3)) & 7);
            *(uint4*)(&T[r * 64 + slot * 8]) = v;
        }
        __syncthreads();
#pragma unroll
        for (int j = 0; j < 2; ++j) {
            int idx = t + j * 256;
            int rr = idx >> 3, cc8 = (idx & 7) * 8;
            u16 tmp[8];
#pragma unroll
            for (int i = 0; i < 8; ++i) {
                int row = cc8 + i;
                int slot = (rr >> 3) ^ ((row ^ (row >> 3)) & 7);
                tmp[i] = T[row * 64 + slot * 8 + (rr & 7)];
            }
            *(uint4*)(vt + ((size_t)z * 128 + dy + rr) * 2048 + sx + cc8) = *(uint4*)tmp;
        }
    }
}

// ---------------- flash attention v7 (causal, GQA 2:1) ----------------
// R13 schedule (double-buffered K/V, ONE barrier per visit), swapped-QK
// in-register softmax (R17-verified, -26 us): lane (g,lr) owns q-row lr;
// row-max = 15 in-lane fmax + 2 shfl; P packed to bf16 in-register; PV
// A-fragments assembled by a 2-round shfl exchange (no P LDS buffer).
__global__ __launch_bounds__(256, 2) void attn7_k(
    const u16* __restrict__ qkv, const u16* __restrict__ vt,
    u16* __restrict__ aout)
{
    __shared__ u16 Kt[2][64 * 128];
    __shared__ u16 Vl[2][128 * 64];

    const int t = threadIdx.x;
    const int lane = t & 63;
    const int w = t >> 6;
    const int g = lane >> 4, lr = lane & 15;
    const int pr = blockIdx.x, h = blockIdx.y, b = blockIdx.z;
    const int hk = h >> 1;
    const size_t rowb = (size_t)b * 2048;

    const u16* ksrc = qkv + rowb * 4096 + 2048 + hk * 128;
    const u16* vsrc = vt + (size_t)(b * 8 + hk) * 128 * 2048;

    bf16x8 ones8;
    {
        union { bf16x8 v; u16 e[8]; } on;
#pragma unroll
        for (int j = 0; j < 8; ++j) on.e[j] = 0x3F80;   // bf16 1.0
        ones8 = on.v;
    }

    auto STAGE = [&](int buf, int kvb) {
#pragma unroll
        for (int j = 0; j < 4; ++j) {
            int idx = t + j * 256;
            {   // K: row = idx>>4 (0..63), slot = idx&15; swizzle low 3 chunk bits
                int row = idx >> 4, slot = idx & 15;
                int csrc = (slot & 8) | ((slot & 7) ^ (row & 7));
                gload16(ksrc + (size_t)(kvb + row) * 4096 + csrc * 8, &Kt[buf][0] + idx * 8);
            }
            {   // V: row = idx>>3 (0..127 d-rows), slot = idx&7
                int row = idx >> 3, slot = idx & 7;
                int csrc = slot ^ (row & 7);
                gload16(vsrc + (size_t)row * 2048 + kvb + csrc * 8, &Vl[buf][0] + idx * 8);
            }
        }
    };

    for (int sub = 0; sub < 2; ++sub) {
        const int qt = sub ? 15 - pr : pr;
        const int qbase = qt * 128;
        const int nt = 2 * qt + 2;

        // Q fragments for both 16-row sub-blocks, pre-scaled by SCALE
        bf16x8 qf[2][4];
        {
            const u16* qp = qkv + (rowb + qbase + w * 32 + lr) * 4096 + h * 128;
#pragma unroll
            for (int sb = 0; sb < 2; ++sb)
#pragma unroll
                for (int c = 0; c < 4; ++c) {
                    union { bf16x8 v; u16 e[8]; } uq;
                    uq.v = *(const bf16x8*)(qp + sb * 16 * 4096 + c * 32 + g * 8);
#pragma unroll
                    for (int jj = 0; jj < 8; ++jj) uq.e[jj] = f2bf(bf2f(uq.e[jj]) * SCALE);
                    qf[sb][c] = uq.v;
                }
        }

        float m_r2[2];                       // running max of THIS lane's q-row
        f32x4 z = {0.f, 0.f, 0.f, 0.f};
        f32x4 l_acc[2];
        f32x4 o_acc[2][8];
#pragma unroll
        for (int sb = 0; sb < 2; ++sb) {
            m_r2[sb] = -INFINITY;
            l_acc[sb] = z;
#pragma unroll
            for (int d = 0; d < 8; ++d) o_acc[sb][d] = z;
        }

        __syncthreads();   // WAR vs previous sub's last-visit reads
        STAGE(0, 0);       // prologue into buf0

        for (int kt = 0; kt < nt; ++kt) {
            const int cur = kt & 1;
            const int kvb = kt * 64;
            asm volatile("s_waitcnt vmcnt(0)" ::: "memory");   // visit-kt loads landed
            __builtin_amdgcn_s_barrier();       // RAW for all waves + WAR for buf[cur^1]
            __builtin_amdgcn_sched_barrier(0);
            if (kt + 1 < nt) STAGE(cur ^ 1, kvb + 64);   // next tile: full-visit flight
            __builtin_amdgcn_sched_barrier(0);

            const u16* Kc = &Kt[cur][0];
            const u16* Vc = &Vl[cur][0];
            const bool active = !(kt == nt - 1 && w < 2);
            const bool near = (kt >= nt - 2);

            if (active) {
                // S^T = K Q^T for both sub-blocks (same fragment reads, swapped roles)
                f32x4 st[2][4];
                __builtin_amdgcn_s_setprio(1);
#pragma unroll
                for (int cb = 0; cb < 4; ++cb) {
                    int row = cb * 16 + lr;
                    st[0][cb] = z; st[1][cb] = z;
#pragma unroll
                    for (int c = 0; c < 4; ++c) {
                        int chunk = c * 4 + g;
                        int slot = (chunk & 8) | ((chunk & 7) ^ (row & 7));
                        bf16x8 kf = *(const bf16x8*)(&Kc[row * 128 + slot * 8]);
                        st[0][cb] = __builtin_amdgcn_mfma_f32_16x16x32_bf16(kf, qf[0][c], st[0][cb], 0, 0, 0);
                        st[1][cb] = __builtin_amdgcn_mfma_f32_16x16x32_bf16(kf, qf[1][c], st[1][cb], 0, 0, 0);
                    }
                }
                __builtin_amdgcn_s_setprio(0);

                const int slo = ((g & 1) << 5) + lr;   // source lane pair for PV assembly
                const int shi = slo + 16;
                const bool ghx = (g >> 1) & 1;         // g in {2,3} -> consume cb = 2kk+1

#pragma unroll
                for (int sb = 0; sb < 2; ++sb) {
                    const int qa = qbase + w * 32 + sb * 16 + lr;   // this lane's q-row
                    if (near) {
#pragma unroll
                        for (int cb = 0; cb < 4; ++cb)
#pragma unroll
                            for (int r = 0; r < 4; ++r)
                                if (kvb + cb * 16 + g * 4 + r > qa) st[sb][cb][r] = -INFINITY;
                    }
                    // row max: 15 in-lane + combine the 4 g-copies
                    f32x4 m4;
#pragma unroll
                    for (int e = 0; e < 4; ++e)
                        m4[e] = fmaxf(fmaxf(st[sb][0][e], st[sb][1][e]),
                                      fmaxf(st[sb][2][e], st[sb][3][e]));
                    float mx = fmaxf(fmaxf(m4[0], m4[1]), fmaxf(m4[2], m4[3]));
                    mx = fmaxf(mx, __shfl_xor(mx, 16));
                    mx = fmaxf(mx, __shfl_xor(mx, 32));
                    float mold = m_r2[sb];
                    float mbase;
                    if (__all(mx <= mold + 8.0f)) {
                        mbase = mold;               // T13 defer-max: skip rescale
                    } else {
                        float mnew = fmaxf(mold, mx);
                        float alpha = __expf(mold - mnew);
#pragma unroll
                        for (int r = 0; r < 4; ++r) {
                            float ar = __shfl(alpha, (lane & 48) | (g * 4 + r), 64);
                            l_acc[sb][r] *= ar;
#pragma unroll
                            for (int d = 0; d < 8; ++d) o_acc[sb][d][r] *= ar;
                        }
                        m_r2[sb] = mnew;
                        mbase = mnew;
                    }
                    // P pack: pk[cb] = bf16(p_r0..p_r3) of this lane's kv slots
                    uint2 pk[4];
#pragma unroll
                    for (int cb = 0; cb < 4; ++cb) {
                        float p0 = __expf(st[sb][cb][0] - mbase);
                        float p1 = __expf(st[sb][cb][1] - mbase);
                        float p2 = __expf(st[sb][cb][2] - mbase);
                        float p3 = __expf(st[sb][cb][3] - mbase);
                        pk[cb].x = (uint32_t)f2bf_n(p0) | ((uint32_t)f2bf_n(p1) << 16);
                        pk[cb].y = (uint32_t)f2bf_n(p2) | ((uint32_t)f2bf_n(p3) << 16);
                    }

                    // O += P V; l += P x ones (pa assembled in-register)
#pragma unroll
                    for (int kk = 0; kk < 2; ++kk) {
                        uint32_t e0 = (uint32_t)__shfl((int)pk[kk * 2].x, slo, 64);
                        uint32_t e1 = (uint32_t)__shfl((int)pk[kk * 2].y, slo, 64);
                        uint32_t e2 = (uint32_t)__shfl((int)pk[kk * 2].x, shi, 64);
                        uint32_t e3 = (uint32_t)__shfl((int)pk[kk * 2].y, shi, 64);
                        uint32_t o0 = (uint32_t)__shfl((int)pk[kk * 2 + 1].x, slo, 64);
                        uint32_t o1 = (uint32_t)__shfl((int)pk[kk * 2 + 1].y, slo, 64);
                        uint32_t o2 = (uint32_t)__shfl((int)pk[kk * 2 + 1].x, shi, 64);
                        uint32_t o3 = (uint32_t)__shfl((int)pk[kk * 2 + 1].y, shi, 64);
                        union { uint32_t u[4]; bf16x8 v; } pa;
                        pa.u[0] = ghx ? o0 : e0;
                        pa.u[1] = ghx ? o1 : e1;
                        pa.u[2] = ghx ? o2 : e2;
                        pa.u[3] = ghx ? o3 : e3;
                        __builtin_amdgcn_s_setprio(1);
                        l_acc[sb] = __builtin_amdgcn_mfma_f32_16x16x32_bf16(pa.v, ones8, l_acc[sb], 0, 0, 0);
#pragma unroll
                        for (int d = 0; d < 8; ++d) {
                            int row = d * 16 + lr;
                            int slot = (kk * 4 + g) ^ (row & 7);
                            bf16x8 vf = *(const bf16x8*)(&Vc[row * 64 + slot * 8]);
                            o_acc[sb][d] = __builtin_amdgcn_mfma_f32_16x16x32_bf16(pa.v, vf, o_acc[sb][d], 0, 0, 0);
                        }
                        __builtin_amdgcn_s_setprio(0);
                    }
                }
            }
            __builtin_amdgcn_sched_barrier(0);
            // no trailing barrier: next visit's entry barrier provides the sync
        }

#pragma unroll
        for (int sb = 0; sb < 2; ++sb) {
            const int qrow0 = qbase + w * 32 + sb * 16 + g * 4;
#pragma unroll
            for (int r = 0; r < 4; ++r) {
                float inv = 1.0f / l_acc[sb][r];
                u16* op = aout + (rowb + qrow0 + r) * 2048 + h * 128;
#pragma unroll
                for (int d = 0; d < 8; ++d)
                    op[d * 16 + lr] = f2bf_n(o_acc[sb][d][r] * inv);
            }
        }
    }
}

// ---------------- launcher ----------------
extern "C" void kernel_launch(void* const* d_in, const int* in_sizes, int n_in,
                              void* d_out, int out_size, void* d_ws, size_t ws_size,
                              hipStream_t stream)
{
    const float* hidden = (const float*)d_in[0];
    const float* qkv_w = (const float*)d_in[7];
    const float* qkv_b = (const float*)d_in[8];
    const float* o_w   = (const float*)d_in[9];
    const float* q_nw  = (const float*)d_in[10];
    const float* k_nw  = (const float*)d_in[11];

    char* ws = (char*)d_ws;
    u16* hid_bf  = (u16*)ws; ws += (size_t)8192 * 2048 * 2;
    u16* wqkv_bf = (u16*)ws; ws += (size_t)4096 * 2048 * 2;
    u16* ow_bf   = (u16*)ws; ws += (size_t)2048 * 2048 * 2;
    u16* qkv_bf  = (u16*)ws; ws += (size_t)8192 * 4096 * 2;
    u16* attn_bf = (u16*)ws; ws += (size_t)8192 * 2048 * 2;
    // vt aliases hid_bf: hidden-bf16 is dead after the QKV GEMM, and every
    // call rewrites hid_bf before use -> deterministic across graph replays.
    u16* vt_bf   = hid_bf;   // needs 16.78 MB < hid_bf's 33.55 MB

    // fused cast of all three f32 operands (dests contiguous at hid_bf)
    cvt_all_k<<<28672, 256, 0, stream>>>(hidden, qkv_w, o_w, hid_bf);

    // qkv = hidden @ qkv_w^T + b   -> bf16 [8192][4096]
    gemm8_nt<<<dim3(16, 32), 512, 0, stream>>>(hid_bf, wqkv_bf, qkv_b,
                                               nullptr, qkv_bf, 8192, 4096, 2048);
    // fused: RMS norm q/k heads (blocks 0..8191) + V transpose (blocks 8192..10239)
    prep_k<<<dim3(10240), 256, 0, stream>>>(qkv_bf, q_nw, k_nw, vt_bf);
    // flash attention -> bf16 [8192][2048]
    attn7_k<<<dim3(8, 16, 4), 256, 0, stream>>>(qkv_bf, vt_bf, attn_bf);
    // out = attn @ o_w^T -> fp32 d_out
    gemm8_nt<<<dim3(8, 32), 512, 0, stream>>>(attn_bf, ow_bf, nullptr,
                                              (float*)d_out, nullptr, 8192, 2048, 2048);
}